// Round 8
// baseline (197.036 us; speedup 1.0000x reference)
//
#include <hip/hip_runtime.h>
#include <hip/hip_bf16.h>
#include <hip/hip_fp8.h>

#define N_ROWS 8192
#define NZ 16384           // rows of Z = [An; Bn]
#define DIM 256
#define TAU_INV 2.0f
#define BT 128             // col tile width
#define AT 64              // row tile height (A strip)
#define NTILE 128          // NZ / BT  (col tiles)
#define NCHUNK 16
#define SEGT 8             // col tiles per segment
#define NSEG 2176          // sum over ri of ceil((128 - (ri>>1))/8)
#define PSTRIDE 2176       // floats/segment: 2*64 row-partials + 8*2*128 col-partials

typedef float f32x4 __attribute__((ext_vector_type(4)));
typedef long lx2 __attribute__((ext_vector_type(2)));   // 16B = 2 fp8 MFMA operands

// ---------------------------------------------------------------------------
// Kernel 1: one WAVE per row. L2-normalize, scale by 16, quantize to OCP fp8
// e4m3, write Z8 K-INTERLEAVED: each 64B chunk stores its eight 8B K-groups
// as [g0 g4 g1 g5 g2 g6 g3 g7] so one 16B granule = operand pair (g, g+4)
// for two consecutive MFMA K-steps. pos[i] = (1/256)*dot(quantized an, bn).
// ---------------------------------------------------------------------------
__global__ __launch_bounds__(256) void normalize_kernel(
    const float* __restrict__ z1, const float* __restrict__ z2,
    unsigned char* __restrict__ Z8, float* __restrict__ pos)
{
    const int tid = threadIdx.x;
    const int wave = tid >> 6;
    const int lane = tid & 63;
    const int row = blockIdx.x * 4 + wave;      // 0..8191

    const float4 a = ((const float4*)(z1 + (size_t)row * DIM))[lane];
    const float4 b = ((const float4*)(z2 + (size_t)row * DIM))[lane];

    auto wsum = [&](float v) -> float {
        #pragma unroll
        for (int m = 1; m < 64; m <<= 1) v += __shfl_xor(v, m, 64);
        return v;
    };

    const float na2 = wsum(a.x*a.x + a.y*a.y + a.z*a.z + a.w*a.w);
    const float nb2 = wsum(b.x*b.x + b.y*b.y + b.z*b.z + b.w*b.w);
    const float sa = 16.0f / sqrtf(na2);   // norms ~16; eps never binds
    const float sb = 16.0f / sqrtf(nb2);

    const float av[4] = {a.x*sa, a.y*sa, a.z*sa, a.w*sa};
    const float bv[4] = {b.x*sb, b.y*sb, b.z*sb, b.w*sb};
    unsigned char pa[4], pb[4];
    float qd = 0.0f;
    #pragma unroll
    for (int k = 0; k < 4; ++k) {
        __hip_fp8_e4m3 qa(av[k]);
        __hip_fp8_e4m3 qb(bv[k]);
        pa[k] = qa.__x; pb[k] = qb.__x;
        qd += float(qa) * float(qb);
    }
    const int g  = (lane >> 1) & 7;
    const int pp = ((g & 3) << 1) | (g >> 2);          // interleaved 8B slot
    const int off = (lane >> 4) * 64 + pp * 8 + (lane & 1) * 4;
    *(uchar4*)(Z8 + (size_t)row * DIM + off) = *(uchar4*)pa;
    *(uchar4*)(Z8 + (size_t)(N_ROWS + row) * DIM + off) = *(uchar4*)pb;

    qd = wsum(qd);
    if (lane == 0) pos[row] = qd * 0.00390625f;   // /256 -> quantized sim
}

// ---------------------------------------------------------------------------
// Kernel 2 (R8 = R4 verbatim schedule + SEGT 8 + 5 blocks/CU):
// symmetric fp8 gram, 64x128 tiles, strip-segmented. Evidence R2-R7: gram
// time tracks ONLY resident-wave count (three different sync schedules all
// ~92us at 28% occ; R4's simple ring at 35% = 80us). So: keep R4's proven
// 2-slot __syncthreads prefetch ring (stage issued right after each sync,
// one full 32-MFMA phase of cover), and push the two cheap levers:
//  - SEGT=8: A-reuse x8, per-segment fixed costs (decode, 16 A-loads, cold
//    first drain, row-partial store) amortize over twice as many tiles.
//  - __launch_bounds__(256,5): 5 x 32KB = exactly the 160KiB LDS pool; if
//    the HW fits 5 blocks/CU -> 20 waves/CU (was 16). If not, falls back
//    to 4 and we keep the amortization win. VGPR ~96 incl acc <= 102 cap.
// A direct global->regs (R5/R7-proven); B ring + swizzle verbatim from R4
// (0 bank conflicts measured). Row partials in regs across the segment;
// col partials reduced+stored per tile (stores drained by the next sync).
// ---------------------------------------------------------------------------
template <bool TWO_STAGE>
__global__ __launch_bounds__(256, 5) void gram_kernel(
    const unsigned char* __restrict__ Z,
    float* __restrict__ part, float* __restrict__ S)
{
    // XCD band remap over segments (2176 = 8 * 272), then segment decode.
    const int sid = (blockIdx.x & 7) * (NSEG / 8) + (blockIdx.x >> 3);
    // group g: strips ri = 16g..16g+15 each have v = 16-g segments;
    // cum(g) = 264g - 8g^2 segments before group g.
    int g = (int)((264.0f - sqrtf(69696.0f - 32.0f * (float)sid)) * 0.0625f);
    g = g < 0 ? 0 : (g > 15 ? 15 : g);
    while (264 * g - 8 * g * g > sid) --g;
    while (g < 15 && 264 * (g + 1) - 8 * (g + 1) * (g + 1) <= sid) ++g;
    const int local = sid - (264 * g - 8 * g * g);
    const int v  = 16 - g;                 // segments per strip in this group
    const int r16 = local / v;
    const int s8 = local - r16 * v;
    const int ri = 16 * g + r16;           // row strip 0..255
    const int tj0 = (ri >> 1) + SEGT * s8; // first col tile
    const int nt = (NTILE - tj0 < SEGT) ? (NTILE - tj0) : SEGT;

    __shared__ unsigned char Ls[32768];   // B ring slots 0/1 (16KB each)

    const int tid  = threadIdx.x;
    const int wave = tid >> 6;
    const int lane = tid & 63;
    const int wr = wave >> 1, wc = wave & 1;   // wave grid 2x2 over 64x128
    const int lm = lane & 15, lq = lane >> 4;

    // ---- A fragments: global -> regs once per segment (R5/R7-proven layout)
    lx2 aR[2][2][2];                       // [kh][set][fr]
    {
        const unsigned char* pa =
            Z + (size_t)(ri * AT + wr * 32 + lm) * DIM + lq * 16;
        #pragma unroll
        for (int fr = 0; fr < 2; ++fr)
            #pragma unroll
            for (int kh = 0; kh < 2; ++kh)
                #pragma unroll
                for (int s = 0; s < 2; ++s)
                    aR[kh][s][fr] =
                        *(const lx2*)(pa + fr * 4096 + kh * 128 + s * 64);
    }

    // ---- staging lane geometry (width-16: 1KB instr = 8 rows x 8 granules)
    const int r8 = lane >> 3;                   // row within 8-row group
    const int pg = lane & 7;                    // LDS granule slot
    const int G0 = pg ^ (r8 >> 1);              // global granule, even instrs
    const int dlt = 64 - ((G0 & 4) << 5);       // odd instrs: granule G0^4
    const unsigned char* pB0 =
        Z + (size_t)(tj0 * BT + wave * 32 + r8) * DIM + (G0 << 4);

    auto stageB = [&](const unsigned char* pb, int kh, int sl) {
        #pragma unroll
        for (int c = 0; c < 4; ++c) {           // rows wave*32 + c*8 + r8
            const unsigned char* gb = ((c & 1) ? pb + dlt : pb) + c * 2048 + kh * 128;
            __builtin_amdgcn_global_load_lds(
                (const __attribute__((address_space(1))) void*)gb,
                (__attribute__((address_space(3))) void*)
                    (Ls + sl * 16384 + (wave * 4 + c) * 1024), 16, 0, 0);
        }
    };

    stageB(pB0, 0, 0);   // prologue: B(tile0, kh0) -> slot0

    // ---- B frag-read bases (invariant across the segment; R4 swizzle)
    const int s0 = (lq ^ (lm >> 1)) << 4;       // slot of granule lq
    const int s1 = s0 ^ 64;                     // slot of granule lq^4
    const unsigned char* LB = Ls + (wc * 64 + lm) * 128;   // + slot*16K

    const float SC = 2.8853900817779268f / 256.0f;   // exp(2*sim), dot=256*sim

    f32x4 rowacc[2] = {};   // per-lane row partial, accumulated over segment

    for (int t = 0; t < nt; ++t) {
        f32x4 acc[2][4] = {};
        #pragma unroll
        for (int kh = 0; kh < 2; ++kh) {
            __syncthreads();    // drains stage(h) [one compute phase of cover]
            if (kh == 0)            stageB(pB0 + (size_t)t * 32768, 1, 1);
            else if (t + 1 < nt)    stageB(pB0 + (size_t)(t + 1) * 32768, 0, 0);

            const unsigned char* lb = LB + (kh << 14);   // slot == kh
            lx2 bP[4];
            __builtin_amdgcn_s_setprio(1);
            #pragma unroll
            for (int f = 0; f < 4; ++f) bP[f] = *(const lx2*)(lb + s0 + f * 2048);
            #pragma unroll
            for (int fr = 0; fr < 2; ++fr)
                #pragma unroll
                for (int fc = 0; fc < 4; ++fc) {
                    acc[fr][fc] = __builtin_amdgcn_mfma_f32_16x16x32_fp8_fp8(
                        aR[kh][0][fr].x, bP[fc].x, acc[fr][fc], 0, 0, 0);
                    acc[fr][fc] = __builtin_amdgcn_mfma_f32_16x16x32_fp8_fp8(
                        aR[kh][0][fr].y, bP[fc].y, acc[fr][fc], 0, 0, 0);
                }
            #pragma unroll
            for (int f = 0; f < 4; ++f) bP[f] = *(const lx2*)(lb + s1 + f * 2048);
            #pragma unroll
            for (int fr = 0; fr < 2; ++fr)
                #pragma unroll
                for (int fc = 0; fc < 4; ++fc) {
                    acc[fr][fc] = __builtin_amdgcn_mfma_f32_16x16x32_fp8_fp8(
                        aR[kh][1][fr].x, bP[fc].x, acc[fr][fc], 0, 0, 0);
                    acc[fr][fc] = __builtin_amdgcn_mfma_f32_16x16x32_fp8_fp8(
                        aR[kh][1][fr].y, bP[fc].y, acc[fr][fc], 0, 0, 0);
                }
            __builtin_amdgcn_s_setprio(0);
        }

        // ---- per-tile epilogue (LDS-free; overlaps in-flight stage)
        #pragma unroll
        for (int fr = 0; fr < 2; ++fr)
            #pragma unroll
            for (int fc = 0; fc < 4; ++fc)
                #pragma unroll
                for (int r = 0; r < 4; ++r)
                    acc[fr][fc][r] = exp2f(acc[fr][fc][r] * SC);

        const int tj = tj0 + t;
        if (tj == (ri >> 1)) {   // only tile of the segment crossing diagonal
            const int add = (ri & 1) << 6;    // odd strip: rows sit 64 below
            #pragma unroll
            for (int fr = 0; fr < 2; ++fr) {
                const int ciloc = wr * 32 + fr * 16 + lq * 4;
                #pragma unroll
                for (int fc = 0; fc < 4; ++fc) {
                    const int cj = wc * 64 + fc * 16 + lm;
                    #pragma unroll
                    for (int r = 0; r < 4; ++r)
                        if (cj <= ciloc + r + add) acc[fr][fc][r] = 0.0f;
                }
            }
        }

        // row partials: accumulate in registers across the segment
        #pragma unroll
        for (int fr = 0; fr < 2; ++fr)
            #pragma unroll
            for (int r = 0; r < 4; ++r)
                rowacc[fr][r] += acc[fr][0][r] + acc[fr][1][r]
                               + acc[fr][2][r] + acc[fr][3][r];

        // col partials per tile (B changes each tile); stores drained by sync
        float* dstc = TWO_STAGE ? (part + (size_t)sid * PSTRIDE + 128 + t * 256)
                                : nullptr;
        #pragma unroll
        for (int fc = 0; fc < 4; ++fc) {
            float s = 0.0f;
            #pragma unroll
            for (int fr = 0; fr < 2; ++fr)
                #pragma unroll
                for (int r = 0; r < 4; ++r) s += acc[fr][fc][r];
            s += __shfl_xor(s, 16, 64);
            s += __shfl_xor(s, 32, 64);
            if (lq == 0) {      // 16 lanes x 4B consecutive = full 64B line
                const int cc = wc * 64 + fc * 16 + lm;
                if (TWO_STAGE) dstc[wr * 128 + cc] = s;
                else atomicAdd(&S[tj * BT + cc], s);
            }
        }
    }

    // ---- segment epilogue: lane-reduce + store row partials ONCE
    float* dstr = TWO_STAGE ? (part + (size_t)sid * PSTRIDE) : nullptr;
    #pragma unroll
    for (int fr = 0; fr < 2; ++fr) {
        f32x4 rs;
        #pragma unroll
        for (int r = 0; r < 4; ++r) {
            float s = rowacc[fr][r];
            s += __shfl_xor(s, 1, 64);
            s += __shfl_xor(s, 2, 64);
            s += __shfl_xor(s, 4, 64);
            s += __shfl_xor(s, 8, 64);
            rs[r] = s;
        }
        if (lm == 0) {          // 4 lanes x 16B consecutive = full 64B line
            const int rr = wr * 32 + fr * 16 + lq * 4;
            if (TWO_STAGE) *(f32x4*)(dstr + wc * 64 + rr) = rs;
            else {
                #pragma unroll
                for (int r = 0; r < 4; ++r)
                    atomicAdd(&S[ri * AT + rr + r], rs[r]);
            }
        }
    }
}

// ---------------------------------------------------------------------------
// Kernel 3: parallel partial gather. grid (NZ/256, NCHUNK).
// Row r: row-side = 2 entries (wc) per segment of strip ri=r>>6;
// col-side = 2 entries (wr) per strip rip = 0..2*tj+1 hitting tile tj=r>>7
// (segment (dtj>>3), in-segment tile dtj&7). All reads coalesced.
// Zeroes out[0].
// ---------------------------------------------------------------------------
__global__ __launch_bounds__(256) void reduce_kernel(
    const float* __restrict__ part, float* __restrict__ S2,
    float* __restrict__ out)
{
    const int chunk = blockIdx.y;
    const int tid = threadIdx.x;
    const int r = blockIdx.x * 256 + tid;       // Z row
    const int ri = r >> 6, rr = r & 63;
    const int gg = ri >> 4;
    const int nseg = 16 - gg;
    const int sid0 = 264 * gg - 8 * gg * gg + (ri & 15) * nseg;
    const int tj = r >> 7, cc = r & 127;
    const int nr = 2 * tj + 2;                  // strips covering col tile tj
    const int T = 2 * nseg + 2 * nr;

    if (chunk == 0 && r == 0) out[0] = 0.0f;

    float s = 0.0f;
    for (int m = chunk; m < T; m += NCHUNK) {
        size_t addr;
        if (m < 2 * nseg) {
            addr = (size_t)(sid0 + (m >> 1)) * PSTRIDE + (m & 1) * 64 + rr;
        } else {
            const int m2 = m - 2 * nseg;
            const int rip = m2 >> 1;            // source strip
            const int dtj = tj - (rip >> 1);
            const int gp = rip >> 4;
            const int sidc = 264 * gp - 8 * gp * gp + (rip & 15) * (16 - gp)
                           + (dtj >> 3);
            addr = (size_t)sidc * PSTRIDE + 128 + (dtj & 7) * 256
                 + (m2 & 1) * 128 + cc;
        }
        s += part[addr];
    }
    S2[(size_t)chunk * NZ + r] = s;
}

// ---------------------------------------------------------------------------
// Kernel 4: loss + mean (two-stage path).
// ---------------------------------------------------------------------------
__global__ __launch_bounds__(256) void loss2_kernel(
    const float* __restrict__ S2, const float* __restrict__ pos,
    float* __restrict__ out)
{
    const int i = blockIdx.x * 256 + threadIdx.x;
    float den1 = 0.0f, den2 = 0.0f;
    #pragma unroll
    for (int c = 0; c < NCHUNK; ++c) {
        den1 += S2[(size_t)c * NZ + i];
        den2 += S2[(size_t)c * NZ + N_ROWS + i];
    }
    float v = 0.5f * (logf(den1) + logf(den2)) - TAU_INV * pos[i];

    __shared__ float red[4];
    #pragma unroll
    for (int m = 1; m < 64; m <<= 1) v += __shfl_xor(v, m, 64);
    if ((threadIdx.x & 63) == 0) red[threadIdx.x >> 6] = v;
    __syncthreads();
    if (threadIdx.x == 0)
        atomicAdd(out, (red[0] + red[1] + red[2] + red[3]) * (1.0f / N_ROWS));
}

// Fallback loss (atomic path, only if ws too small — never expected).
__global__ __launch_bounds__(256) void loss_kernel(
    const float* __restrict__ S, const float* __restrict__ pos,
    float* __restrict__ out)
{
    const int i = blockIdx.x * 256 + threadIdx.x;
    float v = 0.5f * (logf(S[i]) + logf(S[N_ROWS + i])) - TAU_INV * pos[i];

    __shared__ float red[4];
    #pragma unroll
    for (int m = 1; m < 64; m <<= 1) v += __shfl_xor(v, m, 64);
    if ((threadIdx.x & 63) == 0) red[threadIdx.x >> 6] = v;
    __syncthreads();
    if (threadIdx.x == 0)
        atomicAdd(out, (red[0] + red[1] + red[2] + red[3]) * (1.0f / N_ROWS));
}

// ---------------------------------------------------------------------------
extern "C" void kernel_launch(void* const* d_in, const int* in_sizes, int n_in,
                              void* d_out, int out_size, void* d_ws, size_t ws_size,
                              hipStream_t stream)
{
    const float* z1 = (const float*)d_in[0];
    const float* z2 = (const float*)d_in[1];
    float* out = (float*)d_out;

    char* ws = (char*)d_ws;
    unsigned char* Z8 = (unsigned char*)ws;              // 16384*256 = 4 MB
    float* pos  = (float*)(ws + 4194304);                // 32 KB
    float* S2   = (float*)(ws + 4227072);                // 16*16384*4 = 1 MB
    float* part = (float*)(ws + 5275648);                // 2176*2176*4 = 18.9 MB
    const size_t need = 5275648 + (size_t)NSEG * PSTRIDE * 4;

    normalize_kernel<<<N_ROWS / 4, 256, 0, stream>>>(z1, z2, Z8, pos);

    if (ws_size >= need) {
        gram_kernel<true><<<NSEG, 256, 0, stream>>>(Z8, part, nullptr);
        dim3 rg(NZ / 256, NCHUNK);
        reduce_kernel<<<rg, 256, 0, stream>>>(part, S2, out);   // zeroes out
        loss2_kernel<<<N_ROWS / 256, 256, 0, stream>>>(S2, pos, out);
    } else {
        hipMemsetAsync(S2, 0, NZ * sizeof(float), stream);
        hipMemsetAsync(out, 0, sizeof(float), stream);
        gram_kernel<false><<<NSEG, 256, 0, stream>>>(Z8, nullptr, S2);
        loss_kernel<<<N_ROWS / 256, 256, 0, stream>>>(S2, pos, out);
    }
}

// Round 9
// 156.643 us; speedup vs baseline: 1.2579x; 1.2579x over previous
//
#include <hip/hip_runtime.h>
#include <hip/hip_bf16.h>
#include <hip/hip_fp8.h>

#define N_ROWS 8192
#define NZ 16384           // rows of Z = [An; Bn]
#define DIM 256
#define TAU_INV 2.0f
#define BT 128             // col tile width
#define AT 64              // row tile height (A strip)
#define NTILE 128          // NZ / BT  (col tiles)
#define NCHUNK 16
#define SEGT 8             // col tiles per segment
#define NSEG 2176          // sum over ri of ceil((128 - (ri>>1))/8)
#define PSTRIDE 2176       // floats/segment: 2*64 row-partials + 8*2*128 col-partials

typedef float f32x4 __attribute__((ext_vector_type(4)));
typedef long lx2 __attribute__((ext_vector_type(2)));   // 16B = 2 fp8 MFMA operands

// ---------------------------------------------------------------------------
// Kernel 1: one WAVE per row. L2-normalize, scale by 16, quantize to OCP fp8
// e4m3, write Z8 K-INTERLEAVED: each 64B chunk stores its eight 8B K-groups
// as [g0 g4 g1 g5 g2 g6 g3 g7] so one 16B granule = operand pair (g, g+4)
// for two consecutive MFMA K-steps. pos[i] = (1/256)*dot(quantized an, bn).
// ---------------------------------------------------------------------------
__global__ __launch_bounds__(256) void normalize_kernel(
    const float* __restrict__ z1, const float* __restrict__ z2,
    unsigned char* __restrict__ Z8, float* __restrict__ pos)
{
    const int tid = threadIdx.x;
    const int wave = tid >> 6;
    const int lane = tid & 63;
    const int row = blockIdx.x * 4 + wave;      // 0..8191

    const float4 a = ((const float4*)(z1 + (size_t)row * DIM))[lane];
    const float4 b = ((const float4*)(z2 + (size_t)row * DIM))[lane];

    auto wsum = [&](float v) -> float {
        #pragma unroll
        for (int m = 1; m < 64; m <<= 1) v += __shfl_xor(v, m, 64);
        return v;
    };

    const float na2 = wsum(a.x*a.x + a.y*a.y + a.z*a.z + a.w*a.w);
    const float nb2 = wsum(b.x*b.x + b.y*b.y + b.z*b.z + b.w*b.w);
    const float sa = 16.0f / sqrtf(na2);   // norms ~16; eps never binds
    const float sb = 16.0f / sqrtf(nb2);

    const float av[4] = {a.x*sa, a.y*sa, a.z*sa, a.w*sa};
    const float bv[4] = {b.x*sb, b.y*sb, b.z*sb, b.w*sb};
    unsigned char pa[4], pb[4];
    float qd = 0.0f;
    #pragma unroll
    for (int k = 0; k < 4; ++k) {
        __hip_fp8_e4m3 qa(av[k]);
        __hip_fp8_e4m3 qb(bv[k]);
        pa[k] = qa.__x; pb[k] = qb.__x;
        qd += float(qa) * float(qb);
    }
    const int g  = (lane >> 1) & 7;
    const int pp = ((g & 3) << 1) | (g >> 2);          // interleaved 8B slot
    const int off = (lane >> 4) * 64 + pp * 8 + (lane & 1) * 4;
    *(uchar4*)(Z8 + (size_t)row * DIM + off) = *(uchar4*)pa;
    *(uchar4*)(Z8 + (size_t)(N_ROWS + row) * DIM + off) = *(uchar4*)pb;

    qd = wsum(qd);
    if (lane == 0) pos[row] = qd * 0.00390625f;   // /256 -> quantized sim
}

// ---------------------------------------------------------------------------
// Kernel 2 (R9 = R8 with the spill fixed): symmetric fp8 gram, 64x128 tiles,
// strip-segmented, SEGT=8, R4's verbatim 2-slot __syncthreads prefetch ring.
// R8 lesson (Guideline 6): __launch_bounds__(256,5) capped VGPR at ~102 ->
// allocator spilled acc/frags to scratch -> 114MB FETCH / 100MB WRITE of
// HBM scratch traffic, gram 80->128us. Restored (256,4) (cap 128; R7
// measured 72 VGPR for this register set, zero spill). Keep SEGT=8:
// per-segment fixed costs (decode, 16 A-loads, cold first-stage drain,
// row-partial store) amortize over 8 tiles, A-reuse x8.
// A direct global->regs (R5/R7-proven); B ring + swizzle verbatim from R4
// (0 bank conflicts measured). Row partials in regs across the segment;
// col partials reduced+stored per tile (stores drained by the next sync).
// ---------------------------------------------------------------------------
template <bool TWO_STAGE>
__global__ __launch_bounds__(256, 4) void gram_kernel(
    const unsigned char* __restrict__ Z,
    float* __restrict__ part, float* __restrict__ S)
{
    // XCD band remap over segments (2176 = 8 * 272), then segment decode.
    const int sid = (blockIdx.x & 7) * (NSEG / 8) + (blockIdx.x >> 3);
    // group g: strips ri = 16g..16g+15 each have v = 16-g segments;
    // cum(g) = 264g - 8g^2 segments before group g.
    int g = (int)((264.0f - sqrtf(69696.0f - 32.0f * (float)sid)) * 0.0625f);
    g = g < 0 ? 0 : (g > 15 ? 15 : g);
    while (264 * g - 8 * g * g > sid) --g;
    while (g < 15 && 264 * (g + 1) - 8 * (g + 1) * (g + 1) <= sid) ++g;
    const int local = sid - (264 * g - 8 * g * g);
    const int v  = 16 - g;                 // segments per strip in this group
    const int r16 = local / v;
    const int s8 = local - r16 * v;
    const int ri = 16 * g + r16;           // row strip 0..255
    const int tj0 = (ri >> 1) + SEGT * s8; // first col tile
    const int nt = (NTILE - tj0 < SEGT) ? (NTILE - tj0) : SEGT;

    __shared__ unsigned char Ls[32768];   // B ring slots 0/1 (16KB each)

    const int tid  = threadIdx.x;
    const int wave = tid >> 6;
    const int lane = tid & 63;
    const int wr = wave >> 1, wc = wave & 1;   // wave grid 2x2 over 64x128
    const int lm = lane & 15, lq = lane >> 4;

    // ---- A fragments: global -> regs once per segment (R5/R7-proven layout)
    lx2 aR[2][2][2];                       // [kh][set][fr]
    {
        const unsigned char* pa =
            Z + (size_t)(ri * AT + wr * 32 + lm) * DIM + lq * 16;
        #pragma unroll
        for (int fr = 0; fr < 2; ++fr)
            #pragma unroll
            for (int kh = 0; kh < 2; ++kh)
                #pragma unroll
                for (int s = 0; s < 2; ++s)
                    aR[kh][s][fr] =
                        *(const lx2*)(pa + fr * 4096 + kh * 128 + s * 64);
    }

    // ---- staging lane geometry (width-16: 1KB instr = 8 rows x 8 granules)
    const int r8 = lane >> 3;                   // row within 8-row group
    const int pg = lane & 7;                    // LDS granule slot
    const int G0 = pg ^ (r8 >> 1);              // global granule, even instrs
    const int dlt = 64 - ((G0 & 4) << 5);       // odd instrs: granule G0^4
    const unsigned char* pB0 =
        Z + (size_t)(tj0 * BT + wave * 32 + r8) * DIM + (G0 << 4);

    auto stageB = [&](const unsigned char* pb, int kh, int sl) {
        #pragma unroll
        for (int c = 0; c < 4; ++c) {           // rows wave*32 + c*8 + r8
            const unsigned char* gb = ((c & 1) ? pb + dlt : pb) + c * 2048 + kh * 128;
            __builtin_amdgcn_global_load_lds(
                (const __attribute__((address_space(1))) void*)gb,
                (__attribute__((address_space(3))) void*)
                    (Ls + sl * 16384 + (wave * 4 + c) * 1024), 16, 0, 0);
        }
    };

    stageB(pB0, 0, 0);   // prologue: B(tile0, kh0) -> slot0

    // ---- B frag-read bases (invariant across the segment; R4 swizzle)
    const int s0 = (lq ^ (lm >> 1)) << 4;       // slot of granule lq
    const int s1 = s0 ^ 64;                     // slot of granule lq^4
    const unsigned char* LB = Ls + (wc * 64 + lm) * 128;   // + slot*16K

    const float SC = 2.8853900817779268f / 256.0f;   // exp(2*sim), dot=256*sim

    f32x4 rowacc[2] = {};   // per-lane row partial, accumulated over segment

    for (int t = 0; t < nt; ++t) {
        f32x4 acc[2][4] = {};
        #pragma unroll
        for (int kh = 0; kh < 2; ++kh) {
            __syncthreads();    // drains stage(h) [one compute phase of cover]
            if (kh == 0)            stageB(pB0 + (size_t)t * 32768, 1, 1);
            else if (t + 1 < nt)    stageB(pB0 + (size_t)(t + 1) * 32768, 0, 0);

            const unsigned char* lb = LB + (kh << 14);   // slot == kh
            lx2 bP[4];
            __builtin_amdgcn_s_setprio(1);
            #pragma unroll
            for (int f = 0; f < 4; ++f) bP[f] = *(const lx2*)(lb + s0 + f * 2048);
            #pragma unroll
            for (int fr = 0; fr < 2; ++fr)
                #pragma unroll
                for (int fc = 0; fc < 4; ++fc) {
                    acc[fr][fc] = __builtin_amdgcn_mfma_f32_16x16x32_fp8_fp8(
                        aR[kh][0][fr].x, bP[fc].x, acc[fr][fc], 0, 0, 0);
                    acc[fr][fc] = __builtin_amdgcn_mfma_f32_16x16x32_fp8_fp8(
                        aR[kh][0][fr].y, bP[fc].y, acc[fr][fc], 0, 0, 0);
                }
            #pragma unroll
            for (int f = 0; f < 4; ++f) bP[f] = *(const lx2*)(lb + s1 + f * 2048);
            #pragma unroll
            for (int fr = 0; fr < 2; ++fr)
                #pragma unroll
                for (int fc = 0; fc < 4; ++fc) {
                    acc[fr][fc] = __builtin_amdgcn_mfma_f32_16x16x32_fp8_fp8(
                        aR[kh][1][fr].x, bP[fc].x, acc[fr][fc], 0, 0, 0);
                    acc[fr][fc] = __builtin_amdgcn_mfma_f32_16x16x32_fp8_fp8(
                        aR[kh][1][fr].y, bP[fc].y, acc[fr][fc], 0, 0, 0);
                }
            __builtin_amdgcn_s_setprio(0);
        }

        // ---- per-tile epilogue (LDS-free; overlaps in-flight stage)
        #pragma unroll
        for (int fr = 0; fr < 2; ++fr)
            #pragma unroll
            for (int fc = 0; fc < 4; ++fc)
                #pragma unroll
                for (int r = 0; r < 4; ++r)
                    acc[fr][fc][r] = exp2f(acc[fr][fc][r] * SC);

        const int tj = tj0 + t;
        if (tj == (ri >> 1)) {   // only tile of the segment crossing diagonal
            const int add = (ri & 1) << 6;    // odd strip: rows sit 64 below
            #pragma unroll
            for (int fr = 0; fr < 2; ++fr) {
                const int ciloc = wr * 32 + fr * 16 + lq * 4;
                #pragma unroll
                for (int fc = 0; fc < 4; ++fc) {
                    const int cj = wc * 64 + fc * 16 + lm;
                    #pragma unroll
                    for (int r = 0; r < 4; ++r)
                        if (cj <= ciloc + r + add) acc[fr][fc][r] = 0.0f;
                }
            }
        }

        // row partials: accumulate in registers across the segment
        #pragma unroll
        for (int fr = 0; fr < 2; ++fr)
            #pragma unroll
            for (int r = 0; r < 4; ++r)
                rowacc[fr][r] += acc[fr][0][r] + acc[fr][1][r]
                               + acc[fr][2][r] + acc[fr][3][r];

        // col partials per tile (B changes each tile); stores drained by sync
        float* dstc = TWO_STAGE ? (part + (size_t)sid * PSTRIDE + 128 + t * 256)
                                : nullptr;
        #pragma unroll
        for (int fc = 0; fc < 4; ++fc) {
            float s = 0.0f;
            #pragma unroll
            for (int fr = 0; fr < 2; ++fr)
                #pragma unroll
                for (int r = 0; r < 4; ++r) s += acc[fr][fc][r];
            s += __shfl_xor(s, 16, 64);
            s += __shfl_xor(s, 32, 64);
            if (lq == 0) {      // 16 lanes x 4B consecutive = full 64B line
                const int cc = wc * 64 + fc * 16 + lm;
                if (TWO_STAGE) dstc[wr * 128 + cc] = s;
                else atomicAdd(&S[tj * BT + cc], s);
            }
        }
    }

    // ---- segment epilogue: lane-reduce + store row partials ONCE
    float* dstr = TWO_STAGE ? (part + (size_t)sid * PSTRIDE) : nullptr;
    #pragma unroll
    for (int fr = 0; fr < 2; ++fr) {
        f32x4 rs;
        #pragma unroll
        for (int r = 0; r < 4; ++r) {
            float s = rowacc[fr][r];
            s += __shfl_xor(s, 1, 64);
            s += __shfl_xor(s, 2, 64);
            s += __shfl_xor(s, 4, 64);
            s += __shfl_xor(s, 8, 64);
            rs[r] = s;
        }
        if (lm == 0) {          // 4 lanes x 16B consecutive = full 64B line
            const int rr = wr * 32 + fr * 16 + lq * 4;
            if (TWO_STAGE) *(f32x4*)(dstr + wc * 64 + rr) = rs;
            else {
                #pragma unroll
                for (int r = 0; r < 4; ++r)
                    atomicAdd(&S[ri * AT + rr + r], rs[r]);
            }
        }
    }
}

// ---------------------------------------------------------------------------
// Kernel 3: parallel partial gather. grid (NZ/256, NCHUNK).
// Row r: row-side = 2 entries (wc) per segment of strip ri=r>>6;
// col-side = 2 entries (wr) per strip rip = 0..2*tj+1 hitting tile tj=r>>7
// (segment (dtj>>3), in-segment tile dtj&7). All reads coalesced.
// Zeroes out[0].
// ---------------------------------------------------------------------------
__global__ __launch_bounds__(256) void reduce_kernel(
    const float* __restrict__ part, float* __restrict__ S2,
    float* __restrict__ out)
{
    const int chunk = blockIdx.y;
    const int tid = threadIdx.x;
    const int r = blockIdx.x * 256 + tid;       // Z row
    const int ri = r >> 6, rr = r & 63;
    const int gg = ri >> 4;
    const int nseg = 16 - gg;
    const int sid0 = 264 * gg - 8 * gg * gg + (ri & 15) * nseg;
    const int tj = r >> 7, cc = r & 127;
    const int nr = 2 * tj + 2;                  // strips covering col tile tj
    const int T = 2 * nseg + 2 * nr;

    if (chunk == 0 && r == 0) out[0] = 0.0f;

    float s = 0.0f;
    for (int m = chunk; m < T; m += NCHUNK) {
        size_t addr;
        if (m < 2 * nseg) {
            addr = (size_t)(sid0 + (m >> 1)) * PSTRIDE + (m & 1) * 64 + rr;
        } else {
            const int m2 = m - 2 * nseg;
            const int rip = m2 >> 1;            // source strip
            const int dtj = tj - (rip >> 1);
            const int gp = rip >> 4;
            const int sidc = 264 * gp - 8 * gp * gp + (rip & 15) * (16 - gp)
                           + (dtj >> 3);
            addr = (size_t)sidc * PSTRIDE + 128 + (dtj & 7) * 256
                 + (m2 & 1) * 128 + cc;
        }
        s += part[addr];
    }
    S2[(size_t)chunk * NZ + r] = s;
}

// ---------------------------------------------------------------------------
// Kernel 4: loss + mean (two-stage path).
// ---------------------------------------------------------------------------
__global__ __launch_bounds__(256) void loss2_kernel(
    const float* __restrict__ S2, const float* __restrict__ pos,
    float* __restrict__ out)
{
    const int i = blockIdx.x * 256 + threadIdx.x;
    float den1 = 0.0f, den2 = 0.0f;
    #pragma unroll
    for (int c = 0; c < NCHUNK; ++c) {
        den1 += S2[(size_t)c * NZ + i];
        den2 += S2[(size_t)c * NZ + N_ROWS + i];
    }
    float v = 0.5f * (logf(den1) + logf(den2)) - TAU_INV * pos[i];

    __shared__ float red[4];
    #pragma unroll
    for (int m = 1; m < 64; m <<= 1) v += __shfl_xor(v, m, 64);
    if ((threadIdx.x & 63) == 0) red[threadIdx.x >> 6] = v;
    __syncthreads();
    if (threadIdx.x == 0)
        atomicAdd(out, (red[0] + red[1] + red[2] + red[3]) * (1.0f / N_ROWS));
}

// Fallback loss (atomic path, only if ws too small — never expected).
__global__ __launch_bounds__(256) void loss_kernel(
    const float* __restrict__ S, const float* __restrict__ pos,
    float* __restrict__ out)
{
    const int i = blockIdx.x * 256 + threadIdx.x;
    float v = 0.5f * (logf(S[i]) + logf(S[N_ROWS + i])) - TAU_INV * pos[i];

    __shared__ float red[4];
    #pragma unroll
    for (int m = 1; m < 64; m <<= 1) v += __shfl_xor(v, m, 64);
    if ((threadIdx.x & 63) == 0) red[threadIdx.x >> 6] = v;
    __syncthreads();
    if (threadIdx.x == 0)
        atomicAdd(out, (red[0] + red[1] + red[2] + red[3]) * (1.0f / N_ROWS));
}

// ---------------------------------------------------------------------------
extern "C" void kernel_launch(void* const* d_in, const int* in_sizes, int n_in,
                              void* d_out, int out_size, void* d_ws, size_t ws_size,
                              hipStream_t stream)
{
    const float* z1 = (const float*)d_in[0];
    const float* z2 = (const float*)d_in[1];
    float* out = (float*)d_out;

    char* ws = (char*)d_ws;
    unsigned char* Z8 = (unsigned char*)ws;              // 16384*256 = 4 MB
    float* pos  = (float*)(ws + 4194304);                // 32 KB
    float* S2   = (float*)(ws + 4227072);                // 16*16384*4 = 1 MB
    float* part = (float*)(ws + 5275648);                // 2176*2176*4 = 18.9 MB
    const size_t need = 5275648 + (size_t)NSEG * PSTRIDE * 4;

    normalize_kernel<<<N_ROWS / 4, 256, 0, stream>>>(z1, z2, Z8, pos);

    if (ws_size >= need) {
        gram_kernel<true><<<NSEG, 256, 0, stream>>>(Z8, part, nullptr);
        dim3 rg(NZ / 256, NCHUNK);
        reduce_kernel<<<rg, 256, 0, stream>>>(part, S2, out);   // zeroes out
        loss2_kernel<<<N_ROWS / 256, 256, 0, stream>>>(S2, pos, out);
    } else {
        hipMemsetAsync(S2, 0, NZ * sizeof(float), stream);
        hipMemsetAsync(out, 0, sizeof(float), stream);
        gram_kernel<false><<<NSEG, 256, 0, stream>>>(Z8, nullptr, S2);
        loss_kernel<<<N_ROWS / 256, 256, 0, stream>>>(S2, pos, out);
    }
}

// Round 10
// 147.254 us; speedup vs baseline: 1.3381x; 1.0638x over previous
//
#include <hip/hip_runtime.h>
#include <hip/hip_bf16.h>
#include <hip/hip_fp8.h>

#define N_ROWS 8192
#define NZ 16384           // rows of Z = [An; Bn]
#define DIM 256
#define TAU_INV 2.0f
#define BT 128             // col tile width
#define AT 64              // row tile height (A strip)
#define NTILE 128          // NZ / BT  (col tiles)
#define NCHUNK 16
#define SEGT 4             // col tiles per segment (R9 lesson: 8 regressed)
#define NSEG 4224          // sum over ri of ceil((128 - (ri>>1))/4)
#define PSTRIDE 1152       // floats/segment: 2*64 row-partials + 4*2*128 col-partials

typedef float f32x4 __attribute__((ext_vector_type(4)));
typedef long lx2 __attribute__((ext_vector_type(2)));   // 16B = 2 fp8 MFMA operands

// ---------------------------------------------------------------------------
// Kernel 1: one WAVE per row. L2-normalize, scale by 16, quantize to OCP fp8
// e4m3, write Z8 K-INTERLEAVED: each 64B chunk stores its eight 8B K-groups
// as [g0 g4 g1 g5 g2 g6 g3 g7] so one 16B granule = operand pair (g, g+4)
// for two consecutive MFMA K-steps. pos[i] = (1/256)*dot(quantized an, bn).
// ---------------------------------------------------------------------------
__global__ __launch_bounds__(256) void normalize_kernel(
    const float* __restrict__ z1, const float* __restrict__ z2,
    unsigned char* __restrict__ Z8, float* __restrict__ pos)
{
    const int tid = threadIdx.x;
    const int wave = tid >> 6;
    const int lane = tid & 63;
    const int row = blockIdx.x * 4 + wave;      // 0..8191

    const float4 a = ((const float4*)(z1 + (size_t)row * DIM))[lane];
    const float4 b = ((const float4*)(z2 + (size_t)row * DIM))[lane];

    auto wsum = [&](float v) -> float {
        #pragma unroll
        for (int m = 1; m < 64; m <<= 1) v += __shfl_xor(v, m, 64);
        return v;
    };

    const float na2 = wsum(a.x*a.x + a.y*a.y + a.z*a.z + a.w*a.w);
    const float nb2 = wsum(b.x*b.x + b.y*b.y + b.z*b.z + b.w*b.w);
    const float sa = 16.0f / sqrtf(na2);   // norms ~16; eps never binds
    const float sb = 16.0f / sqrtf(nb2);

    const float av[4] = {a.x*sa, a.y*sa, a.z*sa, a.w*sa};
    const float bv[4] = {b.x*sb, b.y*sb, b.z*sb, b.w*sb};
    unsigned char pa[4], pb[4];
    float qd = 0.0f;
    #pragma unroll
    for (int k = 0; k < 4; ++k) {
        __hip_fp8_e4m3 qa(av[k]);
        __hip_fp8_e4m3 qb(bv[k]);
        pa[k] = qa.__x; pb[k] = qb.__x;
        qd += float(qa) * float(qb);
    }
    const int g  = (lane >> 1) & 7;
    const int pp = ((g & 3) << 1) | (g >> 2);          // interleaved 8B slot
    const int off = (lane >> 4) * 64 + pp * 8 + (lane & 1) * 4;
    *(uchar4*)(Z8 + (size_t)row * DIM + off) = *(uchar4*)pa;
    *(uchar4*)(Z8 + (size_t)(N_ROWS + row) * DIM + off) = *(uchar4*)pb;

    qd = wsum(qd);
    if (lane == 0) pos[row] = qd * 0.00390625f;   // /256 -> quantized sim
}

// ---------------------------------------------------------------------------
// Kernel 2 (R10 = R4 verbatim + raw v_exp_f32): symmetric fp8 gram, 64x128
// tiles, strip-segmented SEGT=4, 2-slot __syncthreads prefetch ring, A in
// registers, 32KB LDS -> 4 blocks/CU. R9 lesson: SEGT=8 regressed (tail/
// imbalance beat amortization) -> back to the measured-best R4 config.
// R10 experiment: VALUBusy(55%) > MfmaUtil(33%) every round -> epilogue VALU
// is the busier pipe. exp2f lowers through OCML with denormal-range fixups
// (~5 instr); our args are bounded (|dot*SC| <= 2.89, sim in [-1,1]) so the
// fixup can never trigger -> __builtin_amdgcn_exp2f (1x v_exp_f32) saves
// ~4 VALU x 32 elems per tile-wave (~7us predicted).
// B ring + swizzle verbatim (0 bank conflicts measured). Row partials in
// regs across the segment; col partials reduced+stored per tile.
// ---------------------------------------------------------------------------
template <bool TWO_STAGE>
__global__ __launch_bounds__(256, 4) void gram_kernel(
    const unsigned char* __restrict__ Z,
    float* __restrict__ part, float* __restrict__ S)
{
    // XCD band remap over segments (4224 = 8 * 528), then segment decode.
    const int sid = (blockIdx.x & 7) * (NSEG / 8) + (blockIdx.x >> 3);
    // group g: strips ri = 8g..8g+7 each have v = 32-g segments;
    // cum(g) = 260g - 4g^2 segments before group g.
    int g = (int)((260.0f - sqrtf(67600.0f - 16.0f * (float)sid)) * 0.125f);
    g = g < 0 ? 0 : (g > 31 ? 31 : g);
    while (260 * g - 4 * g * g > sid) --g;
    while (g < 31 && 260 * (g + 1) - 4 * (g + 1) * (g + 1) <= sid) ++g;
    const int local = sid - (260 * g - 4 * g * g);
    const int v  = 32 - g;                 // segments per strip in this group
    const int r8i = local / v;
    const int s4 = local - r8i * v;
    const int ri = 8 * g + r8i;            // row strip 0..255
    const int tj0 = (ri >> 1) + SEGT * s4; // first col tile
    const int nt = (NTILE - tj0 < SEGT) ? (NTILE - tj0) : SEGT;

    __shared__ unsigned char Ls[32768];   // B ring slots 0/1 (16KB each)

    const int tid  = threadIdx.x;
    const int wave = tid >> 6;
    const int lane = tid & 63;
    const int wr = wave >> 1, wc = wave & 1;   // wave grid 2x2 over 64x128
    const int lm = lane & 15, lq = lane >> 4;

    // ---- A fragments: global -> regs once per segment (R5/R7-proven layout)
    lx2 aR[2][2][2];                       // [kh][set][fr]
    {
        const unsigned char* pa =
            Z + (size_t)(ri * AT + wr * 32 + lm) * DIM + lq * 16;
        #pragma unroll
        for (int fr = 0; fr < 2; ++fr)
            #pragma unroll
            for (int kh = 0; kh < 2; ++kh)
                #pragma unroll
                for (int s = 0; s < 2; ++s)
                    aR[kh][s][fr] =
                        *(const lx2*)(pa + fr * 4096 + kh * 128 + s * 64);
    }

    // ---- staging lane geometry (width-16: 1KB instr = 8 rows x 8 granules)
    const int r8 = lane >> 3;                   // row within 8-row group
    const int pg = lane & 7;                    // LDS granule slot
    const int G0 = pg ^ (r8 >> 1);              // global granule, even instrs
    const int dlt = 64 - ((G0 & 4) << 5);       // odd instrs: granule G0^4
    const unsigned char* pB0 =
        Z + (size_t)(tj0 * BT + wave * 32 + r8) * DIM + (G0 << 4);

    auto stageB = [&](const unsigned char* pb, int kh, int sl) {
        #pragma unroll
        for (int c = 0; c < 4; ++c) {           // rows wave*32 + c*8 + r8
            const unsigned char* gb = ((c & 1) ? pb + dlt : pb) + c * 2048 + kh * 128;
            __builtin_amdgcn_global_load_lds(
                (const __attribute__((address_space(1))) void*)gb,
                (__attribute__((address_space(3))) void*)
                    (Ls + sl * 16384 + (wave * 4 + c) * 1024), 16, 0, 0);
        }
    };

    stageB(pB0, 0, 0);   // prologue: B(tile0, kh0) -> slot0

    // ---- B frag-read bases (invariant across the segment; R4 swizzle)
    const int s0 = (lq ^ (lm >> 1)) << 4;       // slot of granule lq
    const int s1 = s0 ^ 64;                     // slot of granule lq^4
    const unsigned char* LB = Ls + (wc * 64 + lm) * 128;   // + slot*16K

    const float SC = 2.8853900817779268f / 256.0f;   // exp(2*sim), dot=256*sim

    f32x4 rowacc[2] = {};   // per-lane row partial, accumulated over segment

    for (int t = 0; t < nt; ++t) {
        f32x4 acc[2][4] = {};
        #pragma unroll
        for (int kh = 0; kh < 2; ++kh) {
            __syncthreads();    // drains stage(h) [one compute phase of cover]
            if (kh == 0)            stageB(pB0 + (size_t)t * 32768, 1, 1);
            else if (t + 1 < nt)    stageB(pB0 + (size_t)(t + 1) * 32768, 0, 0);

            const unsigned char* lb = LB + (kh << 14);   // slot == kh
            lx2 bP[4];
            __builtin_amdgcn_s_setprio(1);
            #pragma unroll
            for (int f = 0; f < 4; ++f) bP[f] = *(const lx2*)(lb + s0 + f * 2048);
            #pragma unroll
            for (int fr = 0; fr < 2; ++fr)
                #pragma unroll
                for (int fc = 0; fc < 4; ++fc) {
                    acc[fr][fc] = __builtin_amdgcn_mfma_f32_16x16x32_fp8_fp8(
                        aR[kh][0][fr].x, bP[fc].x, acc[fr][fc], 0, 0, 0);
                    acc[fr][fc] = __builtin_amdgcn_mfma_f32_16x16x32_fp8_fp8(
                        aR[kh][0][fr].y, bP[fc].y, acc[fr][fc], 0, 0, 0);
                }
            #pragma unroll
            for (int f = 0; f < 4; ++f) bP[f] = *(const lx2*)(lb + s1 + f * 2048);
            #pragma unroll
            for (int fr = 0; fr < 2; ++fr)
                #pragma unroll
                for (int fc = 0; fc < 4; ++fc) {
                    acc[fr][fc] = __builtin_amdgcn_mfma_f32_16x16x32_fp8_fp8(
                        aR[kh][1][fr].x, bP[fc].x, acc[fr][fc], 0, 0, 0);
                    acc[fr][fc] = __builtin_amdgcn_mfma_f32_16x16x32_fp8_fp8(
                        aR[kh][1][fr].y, bP[fc].y, acc[fr][fc], 0, 0, 0);
                }
            __builtin_amdgcn_s_setprio(0);
        }

        // ---- per-tile epilogue (LDS-free; overlaps in-flight stage)
        // raw v_exp_f32: args bounded to +-2.89, fixup-free (R10 experiment)
        #pragma unroll
        for (int fr = 0; fr < 2; ++fr)
            #pragma unroll
            for (int fc = 0; fc < 4; ++fc)
                #pragma unroll
                for (int r = 0; r < 4; ++r)
                    acc[fr][fc][r] = __builtin_amdgcn_exp2f(acc[fr][fc][r] * SC);

        const int tj = tj0 + t;
        if (tj == (ri >> 1)) {   // only tile of the segment crossing diagonal
            const int add = (ri & 1) << 6;    // odd strip: rows sit 64 below
            #pragma unroll
            for (int fr = 0; fr < 2; ++fr) {
                const int ciloc = wr * 32 + fr * 16 + lq * 4;
                #pragma unroll
                for (int fc = 0; fc < 4; ++fc) {
                    const int cj = wc * 64 + fc * 16 + lm;
                    #pragma unroll
                    for (int r = 0; r < 4; ++r)
                        if (cj <= ciloc + r + add) acc[fr][fc][r] = 0.0f;
                }
            }
        }

        // row partials: accumulate in registers across the segment
        #pragma unroll
        for (int fr = 0; fr < 2; ++fr)
            #pragma unroll
            for (int r = 0; r < 4; ++r)
                rowacc[fr][r] += acc[fr][0][r] + acc[fr][1][r]
                               + acc[fr][2][r] + acc[fr][3][r];

        // col partials per tile (B changes each tile); stores drained by sync
        float* dstc = TWO_STAGE ? (part + (size_t)sid * PSTRIDE + 128 + t * 256)
                                : nullptr;
        #pragma unroll
        for (int fc = 0; fc < 4; ++fc) {
            float s = 0.0f;
            #pragma unroll
            for (int fr = 0; fr < 2; ++fr)
                #pragma unroll
                for (int r = 0; r < 4; ++r) s += acc[fr][fc][r];
            s += __shfl_xor(s, 16, 64);
            s += __shfl_xor(s, 32, 64);
            if (lq == 0) {      // 16 lanes x 4B consecutive = full 64B line
                const int cc = wc * 64 + fc * 16 + lm;
                if (TWO_STAGE) dstc[wr * 128 + cc] = s;
                else atomicAdd(&S[tj * BT + cc], s);
            }
        }
    }

    // ---- segment epilogue: lane-reduce + store row partials ONCE
    float* dstr = TWO_STAGE ? (part + (size_t)sid * PSTRIDE) : nullptr;
    #pragma unroll
    for (int fr = 0; fr < 2; ++fr) {
        f32x4 rs;
        #pragma unroll
        for (int r = 0; r < 4; ++r) {
            float s = rowacc[fr][r];
            s += __shfl_xor(s, 1, 64);
            s += __shfl_xor(s, 2, 64);
            s += __shfl_xor(s, 4, 64);
            s += __shfl_xor(s, 8, 64);
            rs[r] = s;
        }
        if (lm == 0) {          // 4 lanes x 16B consecutive = full 64B line
            const int rr = wr * 32 + fr * 16 + lq * 4;
            if (TWO_STAGE) *(f32x4*)(dstr + wc * 64 + rr) = rs;
            else {
                #pragma unroll
                for (int r = 0; r < 4; ++r)
                    atomicAdd(&S[ri * AT + rr + r], rs[r]);
            }
        }
    }
}

// ---------------------------------------------------------------------------
// Kernel 3: parallel partial gather. grid (NZ/256, NCHUNK).
// Row r: row-side = 2 wave-halves per segment of strip ri=r>>6;
// col-side = 2 entries (wr) per strip rip = 0..2*tj+1 hitting tile tj=r>>7.
// All reads coalesced. Zeroes out[0]. (Verified R4/R7 layout, PSTRIDE 1152.)
// ---------------------------------------------------------------------------
__global__ __launch_bounds__(256) void reduce_kernel(
    const float* __restrict__ part, float* __restrict__ S2,
    float* __restrict__ out)
{
    const int chunk = blockIdx.y;
    const int tid = threadIdx.x;
    const int r = blockIdx.x * 256 + tid;       // Z row
    const int ri = r >> 6, rr = r & 63;
    const int gg = ri >> 3;
    const int nseg = 32 - gg;
    const int sid0 = 260 * gg - 4 * gg * gg + (ri & 7) * nseg;
    const int tj = r >> 7, cc = r & 127;
    const int nr = 2 * tj + 2;                  // strips covering col tile tj
    const int T = 2 * nseg + 2 * nr;

    if (chunk == 0 && r == 0) out[0] = 0.0f;

    float s = 0.0f;
    for (int m = chunk; m < T; m += NCHUNK) {
        size_t addr;
        if (m < 2 * nseg) {
            addr = (size_t)(sid0 + (m >> 1)) * PSTRIDE + (m & 1) * 64 + rr;
        } else {
            const int m2 = m - 2 * nseg;
            const int rip = m2 >> 1;            // source strip
            const int dtj = tj - (rip >> 1);
            const int gp = rip >> 3;
            const int sidc = 260 * gp - 4 * gp * gp + (rip & 7) * (32 - gp)
                           + (dtj >> 2);
            addr = (size_t)sidc * PSTRIDE + 128 + (dtj & 3) * 256
                 + (m2 & 1) * 128 + cc;
        }
        s += part[addr];
    }
    S2[(size_t)chunk * NZ + r] = s;
}

// ---------------------------------------------------------------------------
// Kernel 4: loss + mean (two-stage path).
// ---------------------------------------------------------------------------
__global__ __launch_bounds__(256) void loss2_kernel(
    const float* __restrict__ S2, const float* __restrict__ pos,
    float* __restrict__ out)
{
    const int i = blockIdx.x * 256 + threadIdx.x;
    float den1 = 0.0f, den2 = 0.0f;
    #pragma unroll
    for (int c = 0; c < NCHUNK; ++c) {
        den1 += S2[(size_t)c * NZ + i];
        den2 += S2[(size_t)c * NZ + N_ROWS + i];
    }
    float v = 0.5f * (logf(den1) + logf(den2)) - TAU_INV * pos[i];

    __shared__ float red[4];
    #pragma unroll
    for (int m = 1; m < 64; m <<= 1) v += __shfl_xor(v, m, 64);
    if ((threadIdx.x & 63) == 0) red[threadIdx.x >> 6] = v;
    __syncthreads();
    if (threadIdx.x == 0)
        atomicAdd(out, (red[0] + red[1] + red[2] + red[3]) * (1.0f / N_ROWS));
}

// Fallback loss (atomic path, only if ws too small — never expected).
__global__ __launch_bounds__(256) void loss_kernel(
    const float* __restrict__ S, const float* __restrict__ pos,
    float* __restrict__ out)
{
    const int i = blockIdx.x * 256 + threadIdx.x;
    float v = 0.5f * (logf(S[i]) + logf(S[N_ROWS + i])) - TAU_INV * pos[i];

    __shared__ float red[4];
    #pragma unroll
    for (int m = 1; m < 64; m <<= 1) v += __shfl_xor(v, m, 64);
    if ((threadIdx.x & 63) == 0) red[threadIdx.x >> 6] = v;
    __syncthreads();
    if (threadIdx.x == 0)
        atomicAdd(out, (red[0] + red[1] + red[2] + red[3]) * (1.0f / N_ROWS));
}

// ---------------------------------------------------------------------------
extern "C" void kernel_launch(void* const* d_in, const int* in_sizes, int n_in,
                              void* d_out, int out_size, void* d_ws, size_t ws_size,
                              hipStream_t stream)
{
    const float* z1 = (const float*)d_in[0];
    const float* z2 = (const float*)d_in[1];
    float* out = (float*)d_out;

    char* ws = (char*)d_ws;
    unsigned char* Z8 = (unsigned char*)ws;              // 16384*256 = 4 MB
    float* pos  = (float*)(ws + 4194304);                // 32 KB
    float* S2   = (float*)(ws + 4227072);                // 16*16384*4 = 1 MB
    float* part = (float*)(ws + 5275648);                // 4224*1152*4 = 19.5 MB
    const size_t need = 5275648 + (size_t)NSEG * PSTRIDE * 4;

    normalize_kernel<<<N_ROWS / 4, 256, 0, stream>>>(z1, z2, Z8, pos);

    if (ws_size >= need) {
        gram_kernel<true><<<NSEG, 256, 0, stream>>>(Z8, part, nullptr);
        dim3 rg(NZ / 256, NCHUNK);
        reduce_kernel<<<rg, 256, 0, stream>>>(part, S2, out);   // zeroes out
        loss2_kernel<<<N_ROWS / 256, 256, 0, stream>>>(S2, pos, out);
    } else {
        hipMemsetAsync(S2, 0, NZ * sizeof(float), stream);
        hipMemsetAsync(out, 0, sizeof(float), stream);
        gram_kernel<false><<<NSEG, 256, 0, stream>>>(Z8, nullptr, S2);
        loss_kernel<<<N_ROWS / 256, 256, 0, stream>>>(S2, pos, out);
    }
}